// Round 3
// baseline (482.113 us; speedup 1.0000x reference)
//
#include <hip/hip_runtime.h>

// Problem constants
#define N_BATCH 8
#define CI 8
#define CO 16
#define ODIM 66
#define OSP (66*66*66)        // 287496 per (n, co) slab
#define GROUPS 4

typedef _Float16 half8 __attribute__((ext_vector_type(8)));
typedef float f32x4 __attribute__((ext_vector_type(4)));

// MFMA conv tiling: block = (n, od-chunk of 6, 8 oh-rows). 8*66 = 528 positions
// = 33 tiles of 16 -> 3 waves x 11 tiles. K = 28 taps x 8 ci = 7 chunks of 32.
// Sliding window over od with a 3-plane LDS ring (write slot = retiring slot,
// guarded by a 2nd barrier). Barriers are lgkmcnt-only (inline asm): epilogue
// global stores and staging loads stay in flight across od steps (T4: never
// drain vmcnt in the main loop). LDS = 39.9 KB -> 4 blocks/CU -> all 792
// blocks resident in one shot (no tail).
#define OHT 8
#define NWAVES 3
#define TPW 11
#define NTHR 192
#define XIH 10                 // staged ih rows (8 + 2 halo)
#define XIW 68                 // staged iw (64 + 2+2 zero halo)
#define PLPOS (XIH*XIW)        // 680 positions per z-plane
#define PLPAIR (PLPOS/2)       // 340 float2 pair-positions
#define PLH (PLPOS*8)          // 5440 halfs per z-plane (10.88 KB)
#define RING 3                 // 3 active planes; new plane overwrites retiring one
#define LOD 6                  // od planes per block (11 chunks * 6 = 66)
#define NODC 11
#define WSZ (28*16*8)          // 3584 halfs, tap 27 = zero pad
#define XPLANE 262144          // 64*64*64 floats per (n,ci) plane

// lgkmcnt-only barrier: does NOT drain vmcnt (stores/loads keep flying).
#define LGKM_BARRIER() asm volatile("s_waitcnt lgkmcnt(0)\n\ts_barrier" ::: "memory")

// ws layout (floats): [0..31] sum, [32..63] sumsq
__global__ __launch_bounds__(64) void zero_stats(float* ws) {
    ws[threadIdx.x] = 0.0f;
}

// Issue the 16 (2 pair-pos x 8 ci) float2 global loads for one z-plane.
// Lanes consecutive -> pair-positions consecutive -> 8B/lane coalesced.
__device__ __forceinline__ void stage_issue(
    const float* __restrict__ x, size_t nbase, int id, int oh0, int tid,
    float2 xr[2][8], int sp[2], bool sok[2])
{
    #pragma unroll
    for (int it = 0; it < 2; ++it) {
        int p2  = tid + it * NTHR;            // < 384, valid if p2 < 340
        int row = p2 / 34;
        int u   = p2 - row * 34;
        int iw0 = 2 * u - 2;                  // even; pair (iw0, iw0+1)
        int ih  = oh0 - 2 + row;
        bool ok = (p2 < PLPAIR) & ((unsigned)id < 64u) &
                  ((unsigned)ih < 64u) & ((unsigned)iw0 < 63u);
        size_t base = nbase + (ok ? ((size_t)id * 4096 + (size_t)(ih * 64 + iw0)) : 0);
        #pragma unroll
        for (int ci = 0; ci < 8; ++ci)
            xr[it][ci] = *(const float2*)&x[base + (size_t)ci * XPLANE];  // clamped, safe, 8B-aligned
        sp[it] = p2; sok[it] = ok;
    }
}

// Convert + publish one staged plane into ring slot (2x contiguous b128 per
// pair, conflict-free). Caller places this AFTER barrier1 (vmcnt hides under
// the MFMA block since loads were issued before it).
__device__ __forceinline__ void stage_write(
    _Float16* XT, int slot, const float2 xr[2][8], const int sp[2], const bool sok[2])
{
    #pragma unroll
    for (int it = 0; it < 2; ++it) {
        if (sp[it] < PLPAIR) {
            half8 h0, h1;
            #pragma unroll
            for (int ci = 0; ci < 8; ++ci) {
                h0[ci] = sok[it] ? (_Float16)xr[it][ci].x : (_Float16)0.0f;
                h1[ci] = sok[it] ? (_Float16)xr[it][ci].y : (_Float16)0.0f;
            }
            _Float16* dst = &XT[slot * PLH + sp[it] * 16];
            *(half8*)dst = h0;
            *(half8*)(dst + 8) = h1;
        }
    }
}

__global__ __launch_bounds__(NTHR, 3) void conv_mfma(
    const float* __restrict__ x, const float* __restrict__ w,
    float* __restrict__ out, float* __restrict__ stats)
{
    __shared__ _Float16 XT[RING * PLH];   // 32,640 B ring of z-planes [slot][pos][ci]
    __shared__ _Float16 WT[WSZ];          // 7,168 B  [t][co][ci], tap 27 = zeros
    __shared__ float reds[2][NWAVES][GROUPS];

    const int tid = threadIdx.x;
    const int n   = blockIdx.z;
    const int od0 = blockIdx.y * LOD;
    const int oh0 = blockIdx.x * OHT;

    // Stage weights (fp16 round-trip per reference). Thread owns one (t,co).
    for (int i = tid; i < 28 * 16; i += NTHR) {
        int t = i >> 4, co = i & 15;
        half8 h;
        #pragma unroll
        for (int ci = 0; ci < 8; ++ci) {
            float v = (t < 27) ? w[(ci * 16 + co) * 27 + t] : 0.0f;
            h[ci] = (_Float16)v;
        }
        *(half8*)&WT[i * 8] = h;
    }

    const size_t nbase = (size_t)(n * CI) * XPLANE;

    // Prologue: planes j=0..2 (ids od0-2..od0) into ring slots 0..2.
    {
        float2 xr[2][8]; int sp[2]; bool sok[2];
        #pragma unroll
        for (int j = 0; j < 3; ++j) {
            stage_issue(x, nbase, od0 - 2 + j, oh0, tid, xr, sp, sok);
            stage_write(XT, j, xr, sp, sok);
        }
    }
    LGKM_BARRIER();   // WT + 3 planes visible (vmcnt already consumed by cvts)

    const int lane = tid & 63;
    const int wv   = tid >> 6;
    const int q    = lane >> 4;     // tap-within-chunk (A/B k), row-block (D)
    const int col  = lane & 15;     // co (B/D), position m (A)

    // B fragments + per-chunk tap decomposition. t = c*4+q; t=27 clamps to 26
    // for addressing (its bfrag is zero so the A value is irrelevant).
    // TRANSPOSED-CONV FLIP: reference flips w before the correlation, so tap
    // (kd,kh,kw) in original w indexing reads input id = od - kd, ih = oh - kh,
    // iw = ow - kw. Hence plane j = k + (2 - kd)  (NOT k + kd — that bug cost
    // round 2), and sub[] is SUBTRACTED from the (+2,+2)-offset base.
    half8 bfrag[7];
    int sub[7], kdc[7];
    #pragma unroll
    for (int c = 0; c < 7; ++c) {
        int t = c * 4 + q;
        bfrag[c] = *(const half8*)&WT[(t * 16 + col) * 8];
        if (t > 26) t = 26;
        int kd = t / 9, r = t - kd * 9, kh = r / 3, kw = r - kh * 3;
        sub[c] = (kh * XIW + kw) * 8;   // within-plane tap offset (halfs), subtracted
        kdc[c] = 2 - kd;                // plane j = k + (2-kd) -> slot j % 3
    }

    // Within-plane base address per tile: p = (wv*11+i)*16 + col in 8x66 grid.
    int basein[TPW];
    #pragma unroll
    for (int i = 0; i < TPW; ++i) {
        int p   = (wv * TPW + i) * 16 + col;
        int ohl = p / 66, ow = p - ohl * 66;
        basein[i] = ((ohl + 2) * XIW + (ow + 2)) * 8;
    }

    float s = 0.0f, ss = 0.0f;               // stats accumulated across all LOD ods
    const int co = col;
    float* slab0 = out + (size_t)(n * CO + co) * OSP + (size_t)od0 * 4356 + oh0 * 66;

    float2 xr[2][8]; int sp[2]; bool sok[2]; // in-flight staging registers (T14)

    #pragma unroll
    for (int k = 0; k < LOD; ++k) {
        const bool stg = (k < LOD - 1);
        // Issue next plane's loads BEFORE compute: plane j=k+3, id = od0+k+1.
        // The asm barrier's memory clobber pins these before barrier1, so the
        // latency hides under this step's MFMAs + epilogue.
        if (stg) stage_issue(x, nbase, od0 + k + 1, oh0, tid, xr, sp, sok);

        f32x4 acc[TPW];
        #pragma unroll
        for (int i = 0; i < TPW; ++i) acc[i] = (f32x4){0.f, 0.f, 0.f, 0.f};

        int aoffc[7];   // ring slot base + tap offset for this od (compile-time)
        #pragma unroll
        for (int c = 0; c < 7; ++c)
            aoffc[c] = ((k + kdc[c]) % 3) * PLH - sub[c];

        // 77 (ds_read_b128 + MFMA); c outer keeps 11 inner MFMAs independent.
        #pragma unroll
        for (int c = 0; c < 7; ++c) {
            #pragma unroll
            for (int i = 0; i < TPW; ++i) {
                half8 a = *(const half8*)&XT[basein[i] + aoffc[c]];
                acc[i] = __builtin_amdgcn_mfma_f32_16x16x32_f16(a, bfrag[c], acc[i], 0, 0, 0);
            }
        }

        // Epilogue for od = od0+k: ReLU + store (never drained in-loop) + stats.
        float* slab = slab0 + (size_t)k * 4356;
        #pragma unroll
        for (int i = 0; i < TPW; ++i) {
            #pragma unroll
            for (int r = 0; r < 4; ++r) {
                int p   = (wv * TPW + i) * 16 + q * 4 + r;
                int ohl = p / 66, ow = p - ohl * 66;
                if (oh0 + ohl < ODIM) {
                    float v = fmaxf(acc[i][r], 0.0f);
                    slab[ohl * 66 + ow] = v;
                    s += v;
                    ss = fmaf(v, v, ss);
                }
            }
        }

        if (stg) {
            LGKM_BARRIER();                     // barrier1: all waves' reads of slot k%3 done
            stage_write(XT, k % 3, xr, sp, sok); // cvt waits only this step's loads (vmcnt ordered)
            LGKM_BARRIER();                     // barrier2: staged plane visible
        }
    }

    // Reduce: xor16/32 merges lanes with same co; xor1/2 merges the 4 co of a group.
    s += __shfl_xor(s, 16, 64);  ss += __shfl_xor(ss, 16, 64);
    s += __shfl_xor(s, 32, 64);  ss += __shfl_xor(ss, 32, 64);
    s += __shfl_xor(s, 1, 64);   ss += __shfl_xor(ss, 1, 64);
    s += __shfl_xor(s, 2, 64);   ss += __shfl_xor(ss, 2, 64);
    if (lane < 16 && (lane & 3) == 0) {
        reds[0][wv][lane >> 2] = s;
        reds[1][wv][lane >> 2] = ss;
    }
    __syncthreads();
    if (tid < GROUPS) {
        float ts = 0.0f, tss = 0.0f;
        #pragma unroll
        for (int v = 0; v < NWAVES; ++v) { ts += reds[0][v][tid]; tss += reds[1][v][tid]; }
        atomicAdd(&stats[n * GROUPS + tid], ts);
        atomicAdd(&stats[32 + n * GROUPS + tid], tss);
    }
}

// In-place normalize: out = (y - mean) * rstd * gamma + beta.
// finalize folded in: each block derives mean/rstd from the raw sums (cheap).
#define NORM_ITER 8
#define NORM_NTHR 256
__global__ __launch_bounds__(NORM_NTHR) void norm_kernel(
    float* __restrict__ out, const float* __restrict__ ws,
    const float* __restrict__ gamma, const float* __restrict__ beta)
{
    const int slab = blockIdx.y;           // n*16 + co
    const int n  = slab >> 4;
    const int co = slab & 15;
    const int gi = n * GROUPS + (co >> 2);
    const float cnt  = 4.0f * (float)OSP;
    const float mean = ws[gi] / cnt;
    const float var  = ws[32 + gi] / cnt - mean * mean;
    const float rstd = rsqrtf(var + 1e-5f);
    const float scale = rstd * gamma[co];
    const float shift = beta[co] - mean * scale;

    float4* p = (float4*)(out + (size_t)slab * OSP);
    const int base = blockIdx.x * (NORM_NTHR * NORM_ITER) + threadIdx.x;
    #pragma unroll
    for (int it = 0; it < NORM_ITER; ++it) {
        const int idx = base + it * NORM_NTHR;
        if (idx < OSP / 4) {
            float4 v = p[idx];
            v.x = fmaf(v.x, scale, shift);
            v.y = fmaf(v.y, scale, shift);
            v.z = fmaf(v.z, scale, shift);
            v.w = fmaf(v.w, scale, shift);
            p[idx] = v;
        }
    }
}

extern "C" void kernel_launch(void* const* d_in, const int* in_sizes, int n_in,
                              void* d_out, int out_size, void* d_ws, size_t ws_size,
                              hipStream_t stream) {
    const float* x     = (const float*)d_in[0];
    const float* w     = (const float*)d_in[1];
    const float* gamma = (const float*)d_in[2];
    const float* beta  = (const float*)d_in[3];
    float* out = (float*)d_out;
    float* ws  = (float*)d_ws;

    zero_stats<<<1, 64, 0, stream>>>(ws);

    dim3 grid1((ODIM + OHT - 1) / OHT, NODC, N_BATCH);     // (9, 11, 8) = 792 blocks
    conv_mfma<<<grid1, NTHR, 0, stream>>>(x, w, out, ws);

    const int f4_per_slab = OSP / 4;                       // 71874
    dim3 grid2((f4_per_slab + NORM_NTHR * NORM_ITER - 1) / (NORM_NTHR * NORM_ITER),
               N_BATCH * CO);                              // (36, 128)
    norm_kernel<<<grid2, NORM_NTHR, 0, stream>>>(out, ws, gamma, beta);
}

// Round 5
// 447.572 us; speedup vs baseline: 1.0772x; 1.0772x over previous
//
#include <hip/hip_runtime.h>

// Problem constants
#define N_BATCH 8
#define CI 8
#define CO 16
#define ODIM 66
#define OSP (66*66*66)        // 287496 per (n, co) slab
#define GROUPS 4

typedef _Float16 half8 __attribute__((ext_vector_type(8)));
typedef float f32x4 __attribute__((ext_vector_type(4)));

// MFMA conv tiling: block = (n, od-chunk of 6, 8 oh-rows). 8*66 = 528 positions
// = 33 tiles of 16 -> 3 waves x 11 tiles. K = 28 taps x 8 ci = 7 chunks of 32.
// Sliding window over od with a 3-plane LDS ring; lgkmcnt-only barriers keep
// stores/staging loads in flight (T4). REGISTER BUDGET (round-3 lesson): the
// pinned staging regs (xr=32) + acc(44) + bfrag(28) overflowed the allocator's
// budget -> 350 MB of scratch spill traffic (FETCH 54->210, WRITE 147->340 MB).
// Fix: (1) B-fragments re-read from LDS per K-chunk instead of held in 28
// VGPRs; (2) stage_write placed BEFORE the epilogue so xr dies at the barrier.
// Peak live ~110 regs -> no spill at any plausible waves/EU budget.
#define OHT 8
#define NWAVES 3
#define TPW 11
#define NTHR 192
#define XIH 10                 // staged ih rows (8 + 2 halo)
#define XIW 68                 // staged iw (64 + 2+2 zero halo)
#define PLPOS (XIH*XIW)        // 680 positions per z-plane
#define PLPAIR (PLPOS/2)       // 340 float2 pair-positions
#define PLH (PLPOS*8)          // 5440 halfs per z-plane (10.88 KB)
#define RING 3                 // 3 active planes; new plane overwrites retiring one
#define LOD 6                  // od planes per block (11 chunks * 6 = 66)
#define NODC 11
#define WSZ (28*16*8)          // 3584 halfs, tap 27 = zero pad
#define XPLANE 262144          // 64*64*64 floats per (n,ci) plane

// lgkmcnt-only barrier: does NOT drain vmcnt (stores/loads keep flying).
#define LGKM_BARRIER() asm volatile("s_waitcnt lgkmcnt(0)\n\ts_barrier" ::: "memory")

// ws layout (floats): [0..31] sum, [32..63] sumsq
__global__ __launch_bounds__(64) void zero_stats(float* ws) {
    ws[threadIdx.x] = 0.0f;
}

// Issue the 16 (2 pair-pos x 8 ci) float2 global loads for one z-plane.
// Lanes consecutive -> pair-positions consecutive -> 8B/lane coalesced.
__device__ __forceinline__ void stage_issue(
    const float* __restrict__ x, size_t nbase, int id, int oh0, int tid,
    float2 xr[2][8], int sp[2], bool sok[2])
{
    #pragma unroll
    for (int it = 0; it < 2; ++it) {
        int p2  = tid + it * NTHR;            // < 384, valid if p2 < 340
        int row = p2 / 34;
        int u   = p2 - row * 34;
        int iw0 = 2 * u - 2;                  // even; pair (iw0, iw0+1)
        int ih  = oh0 - 2 + row;
        bool ok = (p2 < PLPAIR) & ((unsigned)id < 64u) &
                  ((unsigned)ih < 64u) & ((unsigned)iw0 < 63u);
        size_t base = nbase + (ok ? ((size_t)id * 4096 + (size_t)(ih * 64 + iw0)) : 0);
        #pragma unroll
        for (int ci = 0; ci < 8; ++ci)
            xr[it][ci] = *(const float2*)&x[base + (size_t)ci * XPLANE];  // clamped, safe, 8B-aligned
        sp[it] = p2; sok[it] = ok;
    }
}

// Convert + publish one staged plane into ring slot (2x contiguous b128 per
// pair, conflict-free). Placed between barriers, BEFORE the epilogue, so the
// staging registers die here (round-3 spill lesson).
__device__ __forceinline__ void stage_write(
    _Float16* XT, int slot, const float2 xr[2][8], const int sp[2], const bool sok[2])
{
    #pragma unroll
    for (int it = 0; it < 2; ++it) {
        if (sp[it] < PLPAIR) {
            half8 h0, h1;
            #pragma unroll
            for (int ci = 0; ci < 8; ++ci) {
                h0[ci] = sok[it] ? (_Float16)xr[it][ci].x : (_Float16)0.0f;
                h1[ci] = sok[it] ? (_Float16)xr[it][ci].y : (_Float16)0.0f;
            }
            _Float16* dst = &XT[slot * PLH + sp[it] * 16];
            *(half8*)dst = h0;
            *(half8*)(dst + 8) = h1;
        }
    }
}

__global__ __launch_bounds__(NTHR, 3) void conv_mfma(
    const float* __restrict__ x, const float* __restrict__ w,
    float* __restrict__ out, float* __restrict__ stats)
{
    __shared__ _Float16 XT[RING * PLH];   // 32,640 B ring of z-planes [slot][pos][ci]
    __shared__ _Float16 WT[WSZ];          // 7,168 B  [t][co][ci], tap 27 = zeros
    __shared__ float reds[2][NWAVES][GROUPS];

    const int tid = threadIdx.x;
    const int n   = blockIdx.z;
    const int od0 = blockIdx.y * LOD;
    const int oh0 = blockIdx.x * OHT;

    // Stage weights (fp16 round-trip per reference). Thread owns one (t,co).
    for (int i = tid; i < 28 * 16; i += NTHR) {
        int t = i >> 4, co = i & 15;
        half8 h;
        #pragma unroll
        for (int ci = 0; ci < 8; ++ci) {
            float v = (t < 27) ? w[(ci * 16 + co) * 27 + t] : 0.0f;
            h[ci] = (_Float16)v;
        }
        *(half8*)&WT[i * 8] = h;
    }

    const size_t nbase = (size_t)(n * CI) * XPLANE;

    // Prologue: planes j=0..2 (ids od0-2..od0) into ring slots 0..2.
    {
        float2 xr[2][8]; int sp[2]; bool sok[2];
        #pragma unroll
        for (int j = 0; j < 3; ++j) {
            stage_issue(x, nbase, od0 - 2 + j, oh0, tid, xr, sp, sok);
            stage_write(XT, j, xr, sp, sok);
        }
    }
    LGKM_BARRIER();   // WT + 3 planes visible (vmcnt already consumed by cvts)

    const int lane = tid & 63;
    const int wv   = tid >> 6;
    const int q    = lane >> 4;     // tap-within-chunk (A/B k), row-block (D)
    const int col  = lane & 15;     // co (B/D), position m (A)

    // Per-chunk tap decomposition. t = c*4+q; t=27 clamps to 26 for addressing
    // (its WT row is zero so the A value is irrelevant).
    // TRANSPOSED-CONV FLIP: reference flips w before the correlation, so tap
    // (kd,kh,kw) in original w indexing reads input id = od - kd, ih = oh - kh,
    // iw = ow - kw. Hence plane j = k + (2 - kd)  (NOT k + kd — that bug cost
    // round 2), and sub[] is SUBTRACTED from the (+2,+2)-offset base.
    int sub[7], kdc[7];
    #pragma unroll
    for (int c = 0; c < 7; ++c) {
        int t = c * 4 + q;
        if (t > 26) t = 26;
        int kd = t / 9, r = t - kd * 9, kh = r / 3, kw = r - kh * 3;
        sub[c] = (kh * XIW + kw) * 8;   // within-plane tap offset (halfs), subtracted
        kdc[c] = 2 - kd;                // plane j = k + (2-kd) -> slot j % 3
    }
    // B-fragment LDS base for this lane: WT[(t*16+col)*8], t = c*4+q.
    const int wtb = (q * 16 + col) * 8;   // + c*512 per chunk

    // Within-plane base address per tile: p = (wv*11+i)*16 + col in 8x66 grid.
    int basein[TPW];
    #pragma unroll
    for (int i = 0; i < TPW; ++i) {
        int p   = (wv * TPW + i) * 16 + col;
        int ohl = p / 66, ow = p - ohl * 66;
        basein[i] = ((ohl + 2) * XIW + (ow + 2)) * 8;
    }

    float s = 0.0f, ss = 0.0f;               // stats accumulated across all LOD ods
    const int co = col;
    float* slab0 = out + (size_t)(n * CO + co) * OSP + (size_t)od0 * 4356 + oh0 * 66;

    float2 xr[2][8]; int sp[2]; bool sok[2]; // in-flight staging registers (T14)

    #pragma unroll
    for (int k = 0; k < LOD; ++k) {
        const bool stg = (k < LOD - 1);
        // Issue next plane's loads BEFORE compute: plane j=k+3, id = od0+k+1.
        // The asm barrier's memory clobber pins these before barrier1, so the
        // latency hides under this step's MFMA block.
        if (stg) stage_issue(x, nbase, od0 + k + 1, oh0, tid, xr, sp, sok);

        f32x4 acc[TPW];
        #pragma unroll
        for (int i = 0; i < TPW; ++i) acc[i] = (f32x4){0.f, 0.f, 0.f, 0.f};

        int aoffc[7];   // ring slot base + tap offset for this od (compile-time)
        #pragma unroll
        for (int c = 0; c < 7; ++c)
            aoffc[c] = ((k + kdc[c]) % 3) * PLH - sub[c];

        // 7 chunks x (1 bfrag ds_read + 11 a ds_read + 11 MFMA); c outer keeps
        // the 11 inner MFMAs independent. bfrag comes from LDS each chunk
        // (saves 28 live VGPRs; WT is read-only so barrier-safe).
        #pragma unroll
        for (int c = 0; c < 7; ++c) {
            half8 bf = *(const half8*)&WT[wtb + c * 512];
            #pragma unroll
            for (int i = 0; i < TPW; ++i) {
                half8 a = *(const half8*)&XT[basein[i] + aoffc[c]];
                acc[i] = __builtin_amdgcn_mfma_f32_16x16x32_f16(a, bf, acc[i], 0, 0, 0);
            }
        }

        // Publish staged plane FIRST (xr dies here; round-3 spill lesson),
        // then the epilogue runs outside the xr live range.
        if (stg) {
            LGKM_BARRIER();                     // barrier1: all waves done reading slot k%3
            stage_write(XT, k % 3, xr, sp, sok); // cvt waits only this step's loads
            LGKM_BARRIER();                     // barrier2: staged plane visible
        }

        // Epilogue for od = od0+k: ReLU + store (never drained in-loop) + stats.
        float* slab = slab0 + (size_t)k * 4356;
        #pragma unroll
        for (int i = 0; i < TPW; ++i) {
            #pragma unroll
            for (int r = 0; r < 4; ++r) {
                int p   = (wv * TPW + i) * 16 + q * 4 + r;
                int ohl = p / 66, ow = p - ohl * 66;
                if (oh0 + ohl < ODIM) {
                    float v = fmaxf(acc[i][r], 0.0f);
                    slab[ohl * 66 + ow] = v;
                    s += v;
                    ss = fmaf(v, v, ss);
                }
            }
        }
    }

    // Reduce: xor16/32 merges lanes with same co; xor1/2 merges the 4 co of a group.
    s += __shfl_xor(s, 16, 64);  ss += __shfl_xor(ss, 16, 64);
    s += __shfl_xor(s, 32, 64);  ss += __shfl_xor(ss, 32, 64);
    s += __shfl_xor(s, 1, 64);   ss += __shfl_xor(ss, 1, 64);
    s += __shfl_xor(s, 2, 64);   ss += __shfl_xor(ss, 2, 64);
    if (lane < 16 && (lane & 3) == 0) {
        reds[0][wv][lane >> 2] = s;
        reds[1][wv][lane >> 2] = ss;
    }
    __syncthreads();
    if (tid < GROUPS) {
        float ts = 0.0f, tss = 0.0f;
        #pragma unroll
        for (int v = 0; v < NWAVES; ++v) { ts += reds[0][v][tid]; tss += reds[1][v][tid]; }
        atomicAdd(&stats[n * GROUPS + tid], ts);
        atomicAdd(&stats[32 + n * GROUPS + tid], tss);
    }
}

// In-place normalize: out = (y - mean) * rstd * gamma + beta.
// finalize folded in: each block derives mean/rstd from the raw sums (cheap).
#define NORM_ITER 8
#define NORM_NTHR 256
__global__ __launch_bounds__(NORM_NTHR) void norm_kernel(
    float* __restrict__ out, const float* __restrict__ ws,
    const float* __restrict__ gamma, const float* __restrict__ beta)
{
    const int slab = blockIdx.y;           // n*16 + co
    const int n  = slab >> 4;
    const int co = slab & 15;
    const int gi = n * GROUPS + (co >> 2);
    const float cnt  = 4.0f * (float)OSP;
    const float mean = ws[gi] / cnt;
    const float var  = ws[32 + gi] / cnt - mean * mean;
    const float rstd = rsqrtf(var + 1e-5f);
    const float scale = rstd * gamma[co];
    const float shift = beta[co] - mean * scale;

    float4* p = (float4*)(out + (size_t)slab * OSP);
    const int base = blockIdx.x * (NORM_NTHR * NORM_ITER) + threadIdx.x;
    #pragma unroll
    for (int it = 0; it < NORM_ITER; ++it) {
        const int idx = base + it * NORM_NTHR;
        if (idx < OSP / 4) {
            float4 v = p[idx];
            v.x = fmaf(v.x, scale, shift);
            v.y = fmaf(v.y, scale, shift);
            v.z = fmaf(v.z, scale, shift);
            v.w = fmaf(v.w, scale, shift);
            p[idx] = v;
        }
    }
}

extern "C" void kernel_launch(void* const* d_in, const int* in_sizes, int n_in,
                              void* d_out, int out_size, void* d_ws, size_t ws_size,
                              hipStream_t stream) {
    const float* x     = (const float*)d_in[0];
    const float* w     = (const float*)d_in[1];
    const float* gamma = (const float*)d_in[2];
    const float* beta  = (const float*)d_in[3];
    float* out = (float*)d_out;
    float* ws  = (float*)d_ws;

    zero_stats<<<1, 64, 0, stream>>>(ws);

    dim3 grid1((ODIM + OHT - 1) / OHT, NODC, N_BATCH);     // (9, 11, 8) = 792 blocks
    conv_mfma<<<grid1, NTHR, 0, stream>>>(x, w, out, ws);

    const int f4_per_slab = OSP / 4;                       // 71874
    dim3 grid2((f4_per_slab + NORM_NTHR * NORM_ITER - 1) / (NORM_NTHR * NORM_ITER),
               N_BATCH * CO);                              // (36, 128)
    norm_kernel<<<grid2, NORM_NTHR, 0, stream>>>(out, ws, gamma, beta);
}

// Round 7
// 345.627 us; speedup vs baseline: 1.3949x; 1.2950x over previous
//
#include <hip/hip_runtime.h>

// Problem constants
#define N_BATCH 8
#define CI 8
#define CO 16
#define ODIM 66
#define OSP (66*66*66)        // 287496 per (n, co) slab
#define GROUPS 4

typedef _Float16 half8 __attribute__((ext_vector_type(8)));
typedef float f32x4 __attribute__((ext_vector_type(4)));

// MFMA conv tiling: block = (n, od-chunk of 6, 8 oh-rows). 8*66 = 528 positions
// = 33 tiles of 16 -> 3 waves x 11 tiles. K = 28 taps x 8 ci = 7 chunks of 32.
// Sliding window over od with a 3-plane LDS ring; lgkmcnt-only barriers keep
// stores/staging loads in flight (T4).
//
// REGISTER BUDGET (rounds 3-5 lesson): WRITE_SIZE responding to register edits
// proved scratch spill (out writes are algorithmically fixed at 147 MB; rounds
// 3/5 measured 340/283 MB). Worst-point live set ~110 arch VGPR + 44 AGPR acc
// in the UNIFIED gfx950 file; __launch_bounds__(192,3) caps arch+acc at ~168
// and full unroll of the LOD loop balloons cross-step demand -> spill.
// Fix: (a) launch_bounds(192,2) -> cap 256; allocator allocates ~demand
// (~130-150), which stays <= 170 so LDS-limited 4 blocks/CU residency holds;
// (b) k-loop NOT unrolled (one body copy, incremental ring index, no modulo).
#define OHT 8
#define NWAVES 3
#define TPW 11
#define NTHR 192
#define XIH 10                 // staged ih rows (8 + 2 halo)
#define XIW 68                 // staged iw (64 + 2+2 zero halo)
#define PLPOS (XIH*XIW)        // 680 positions per z-plane
#define PLPAIR (PLPOS/2)       // 340 float2 pair-positions
#define PLH (PLPOS*8)          // 5440 halfs per z-plane (10.88 KB)
#define RING 3                 // 3 active planes; new plane overwrites retiring one
#define LOD 6                  // od planes per block (11 chunks * 6 = 66)
#define NODC 11
#define WSZ (28*16*8)          // 3584 halfs, tap 27 = zero pad
#define XPLANE 262144          // 64*64*64 floats per (n,ci) plane

// lgkmcnt-only barrier: does NOT drain vmcnt (stores/loads keep flying).
#define LGKM_BARRIER() asm volatile("s_waitcnt lgkmcnt(0)\n\ts_barrier" ::: "memory")

// ws layout (floats): [0..31] sum, [32..63] sumsq
__global__ __launch_bounds__(64) void zero_stats(float* ws) {
    ws[threadIdx.x] = 0.0f;
}

// Issue the 16 (2 pair-pos x 8 ci) float2 global loads for one z-plane.
// Lanes consecutive -> pair-positions consecutive -> 8B/lane coalesced.
__device__ __forceinline__ void stage_issue(
    const float* __restrict__ x, size_t nbase, int id, int oh0, int tid,
    float2 xr[2][8], int sp[2], bool sok[2])
{
    #pragma unroll
    for (int it = 0; it < 2; ++it) {
        int p2  = tid + it * NTHR;            // < 384, valid if p2 < 340
        int row = p2 / 34;
        int u   = p2 - row * 34;
        int iw0 = 2 * u - 2;                  // even; pair (iw0, iw0+1)
        int ih  = oh0 - 2 + row;
        bool ok = (p2 < PLPAIR) & ((unsigned)id < 64u) &
                  ((unsigned)ih < 64u) & ((unsigned)iw0 < 63u);
        size_t base = nbase + (ok ? ((size_t)id * 4096 + (size_t)(ih * 64 + iw0)) : 0);
        #pragma unroll
        for (int ci = 0; ci < 8; ++ci)
            xr[it][ci] = *(const float2*)&x[base + (size_t)ci * XPLANE];  // clamped, safe, 8B-aligned
        sp[it] = p2; sok[it] = ok;
    }
}

// Convert + publish one staged plane into ring slot (2x contiguous b128 per
// pair, conflict-free). Placed between barriers, BEFORE the epilogue, so the
// staging registers die here (round-3 spill lesson).
__device__ __forceinline__ void stage_write(
    _Float16* XT, int slot, const float2 xr[2][8], const int sp[2], const bool sok[2])
{
    #pragma unroll
    for (int it = 0; it < 2; ++it) {
        if (sp[it] < PLPAIR) {
            half8 h0, h1;
            #pragma unroll
            for (int ci = 0; ci < 8; ++ci) {
                h0[ci] = sok[it] ? (_Float16)xr[it][ci].x : (_Float16)0.0f;
                h1[ci] = sok[it] ? (_Float16)xr[it][ci].y : (_Float16)0.0f;
            }
            _Float16* dst = &XT[slot * PLH + sp[it] * 16];
            *(half8*)dst = h0;
            *(half8*)(dst + 8) = h1;
        }
    }
}

__global__ __launch_bounds__(NTHR, 2) void conv_mfma(
    const float* __restrict__ x, const float* __restrict__ w,
    float* __restrict__ out, float* __restrict__ stats)
{
    __shared__ _Float16 XT[RING * PLH];   // 32,640 B ring of z-planes [slot][pos][ci]
    __shared__ _Float16 WT[WSZ];          // 7,168 B  [t][co][ci], tap 27 = zeros
    __shared__ float reds[2][NWAVES][GROUPS];

    const int tid = threadIdx.x;
    const int n   = blockIdx.z;
    const int od0 = blockIdx.y * LOD;
    const int oh0 = blockIdx.x * OHT;

    // Stage weights (fp16 round-trip per reference). Thread owns one (t,co).
    for (int i = tid; i < 28 * 16; i += NTHR) {
        int t = i >> 4, co = i & 15;
        half8 h;
        #pragma unroll
        for (int ci = 0; ci < 8; ++ci) {
            float v = (t < 27) ? w[(ci * 16 + co) * 27 + t] : 0.0f;
            h[ci] = (_Float16)v;
        }
        *(half8*)&WT[i * 8] = h;
    }

    const size_t nbase = (size_t)(n * CI) * XPLANE;

    // Prologue: planes j=0..2 (ids od0-2..od0) into ring slots 0..2.
    {
        float2 xr[2][8]; int sp[2]; bool sok[2];
        #pragma unroll
        for (int j = 0; j < 3; ++j) {
            stage_issue(x, nbase, od0 - 2 + j, oh0, tid, xr, sp, sok);
            stage_write(XT, j, xr, sp, sok);
        }
    }
    LGKM_BARRIER();   // WT + 3 planes visible (vmcnt already consumed by cvts)

    const int lane = tid & 63;
    const int wv   = tid >> 6;
    const int q    = lane >> 4;     // tap-within-chunk (A/B k), row-block (D)
    const int col  = lane & 15;     // co (B/D), position m (A)

    // Per-chunk tap decomposition. t = c*4+q; t=27 clamps to 26 for addressing
    // (its WT row is zero so the A value is irrelevant).
    // TRANSPOSED-CONV FLIP: reference flips w before the correlation, so tap
    // (kd,kh,kw) in original w indexing reads input id = od - kd, ih = oh - kh,
    // iw = ow - kw. Hence plane j = k + (2 - kd)  (NOT k + kd — that bug cost
    // round 2), and sub[] is SUBTRACTED from the (+2,+2)-offset base.
    int sub[7], kdc[7];
    #pragma unroll
    for (int c = 0; c < 7; ++c) {
        int t = c * 4 + q;
        if (t > 26) t = 26;
        int kd = t / 9, r = t - kd * 9, kh = r / 3, kw = r - kh * 3;
        sub[c] = (kh * XIW + kw) * 8;   // within-plane tap offset (halfs), subtracted
        kdc[c] = 2 - kd;                // plane j = k + (2-kd) -> slot (km3+kdc) wrap 3
    }
    // B-fragment LDS base for this lane: WT[(t*16+col)*8], t = c*4+q.
    const int wtb = (q * 16 + col) * 8;   // + c*512 per chunk

    // Within-plane base address per tile: p = (wv*11+i)*16 + col in 8x66 grid.
    int basein[TPW];
    #pragma unroll
    for (int i = 0; i < TPW; ++i) {
        int p   = (wv * TPW + i) * 16 + col;
        int ohl = p / 66, ow = p - ohl * 66;
        basein[i] = ((ohl + 2) * XIW + (ow + 2)) * 8;
    }

    float s = 0.0f, ss = 0.0f;               // stats accumulated across all LOD ods
    const int co = col;
    float* slab = out + (size_t)(n * CO + co) * OSP + (size_t)od0 * 4356 + oh0 * 66;

    float2 xr[2][8]; int sp[2]; bool sok[2]; // in-flight staging registers (T14)
    int km3 = 0;                             // k mod 3, maintained incrementally

    #pragma unroll 1
    for (int k = 0; k < LOD; ++k) {
        const bool stg = (k < LOD - 1);
        // Issue next plane's loads BEFORE compute: id = od0+k+1 into slot km3.
        // The asm barrier's memory clobber pins these before barrier1, so the
        // latency hides under this step's MFMA block.
        if (stg) stage_issue(x, nbase, od0 + k + 1, oh0, tid, xr, sp, sok);

        f32x4 acc[TPW];
        #pragma unroll
        for (int i = 0; i < TPW; ++i) acc[i] = (f32x4){0.f, 0.f, 0.f, 0.f};

        int aoffc[7];   // ring slot base + tap offset for this od
        #pragma unroll
        for (int c = 0; c < 7; ++c) {
            int slot = km3 + kdc[c];
            slot = (slot >= 3) ? slot - 3 : slot;
            aoffc[c] = slot * PLH - sub[c];
        }

        // 7 chunks x (1 bfrag ds_read + 11 a ds_read + 11 MFMA); c outer keeps
        // the 11 inner MFMAs independent. bfrag comes from LDS each chunk
        // (saves 28 live VGPRs; WT is read-only so barrier-safe).
        #pragma unroll
        for (int c = 0; c < 7; ++c) {
            half8 bf = *(const half8*)&WT[wtb + c * 512];
            #pragma unroll
            for (int i = 0; i < TPW; ++i) {
                half8 a = *(const half8*)&XT[basein[i] + aoffc[c]];
                acc[i] = __builtin_amdgcn_mfma_f32_16x16x32_f16(a, bf, acc[i], 0, 0, 0);
            }
        }

        // Publish staged plane FIRST (xr dies here; round-3 spill lesson),
        // then the epilogue runs outside the xr live range.
        if (stg) {
            LGKM_BARRIER();                   // barrier1: all waves done reading slot km3
            stage_write(XT, km3, xr, sp, sok); // cvt waits only this step's loads
            LGKM_BARRIER();                   // barrier2: staged plane visible
        }

        // Epilogue for od = od0+k: ReLU + store (never drained in-loop) + stats.
        #pragma unroll
        for (int i = 0; i < TPW; ++i) {
            #pragma unroll
            for (int r = 0; r < 4; ++r) {
                int p   = (wv * TPW + i) * 16 + q * 4 + r;
                int ohl = p / 66, ow = p - ohl * 66;
                if (oh0 + ohl < ODIM) {
                    float v = fmaxf(acc[i][r], 0.0f);
                    slab[ohl * 66 + ow] = v;
                    s += v;
                    ss = fmaf(v, v, ss);
                }
            }
        }

        slab += 4356;
        km3 = (km3 == 2) ? 0 : km3 + 1;
    }

    // Reduce: xor16/32 merges lanes with same co; xor1/2 merges the 4 co of a group.
    s += __shfl_xor(s, 16, 64);  ss += __shfl_xor(ss, 16, 64);
    s += __shfl_xor(s, 32, 64);  ss += __shfl_xor(ss, 32, 64);
    s += __shfl_xor(s, 1, 64);   ss += __shfl_xor(ss, 1, 64);
    s += __shfl_xor(s, 2, 64);   ss += __shfl_xor(ss, 2, 64);
    if (lane < 16 && (lane & 3) == 0) {
        reds[0][wv][lane >> 2] = s;
        reds[1][wv][lane >> 2] = ss;
    }
    __syncthreads();
    if (tid < GROUPS) {
        float ts = 0.0f, tss = 0.0f;
        #pragma unroll
        for (int v = 0; v < NWAVES; ++v) { ts += reds[0][v][tid]; tss += reds[1][v][tid]; }
        atomicAdd(&stats[n * GROUPS + tid], ts);
        atomicAdd(&stats[32 + n * GROUPS + tid], tss);
    }
}

// In-place normalize: out = (y - mean) * rstd * gamma + beta.
// finalize folded in: each block derives mean/rstd from the raw sums (cheap).
#define NORM_ITER 8
#define NORM_NTHR 256
__global__ __launch_bounds__(NORM_NTHR) void norm_kernel(
    float* __restrict__ out, const float* __restrict__ ws,
    const float* __restrict__ gamma, const float* __restrict__ beta)
{
    const int slab = blockIdx.y;           // n*16 + co
    const int n  = slab >> 4;
    const int co = slab & 15;
    const int gi = n * GROUPS + (co >> 2);
    const float cnt  = 4.0f * (float)OSP;
    const float mean = ws[gi] / cnt;
    const float var  = ws[32 + gi] / cnt - mean * mean;
    const float rstd = rsqrtf(var + 1e-5f);
    const float scale = rstd * gamma[co];
    const float shift = beta[co] - mean * scale;

    float4* p = (float4*)(out + (size_t)slab * OSP);
    const int base = blockIdx.x * (NORM_NTHR * NORM_ITER) + threadIdx.x;
    #pragma unroll
    for (int it = 0; it < NORM_ITER; ++it) {
        const int idx = base + it * NORM_NTHR;
        if (idx < OSP / 4) {
            float4 v = p[idx];
            v.x = fmaf(v.x, scale, shift);
            v.y = fmaf(v.y, scale, shift);
            v.z = fmaf(v.z, scale, shift);
            v.w = fmaf(v.w, scale, shift);
            p[idx] = v;
        }
    }
}

extern "C" void kernel_launch(void* const* d_in, const int* in_sizes, int n_in,
                              void* d_out, int out_size, void* d_ws, size_t ws_size,
                              hipStream_t stream) {
    const float* x     = (const float*)d_in[0];
    const float* w     = (const float*)d_in[1];
    const float* gamma = (const float*)d_in[2];
    const float* beta  = (const float*)d_in[3];
    float* out = (float*)d_out;
    float* ws  = (float*)d_ws;

    zero_stats<<<1, 64, 0, stream>>>(ws);

    dim3 grid1((ODIM + OHT - 1) / OHT, NODC, N_BATCH);     // (9, 11, 8) = 792 blocks
    conv_mfma<<<grid1, NTHR, 0, stream>>>(x, w, out, ws);

    const int f4_per_slab = OSP / 4;                       // 71874
    dim3 grid2((f4_per_slab + NORM_NTHR * NORM_ITER - 1) / (NORM_NTHR * NORM_ITER),
               N_BATCH * CO);                              // (36, 128)
    norm_kernel<<<grid2, NORM_NTHR, 0, stream>>>(out, ws, gamma, beta);
}

// Round 8
// 283.294 us; speedup vs baseline: 1.7018x; 1.2200x over previous
//
#include <hip/hip_runtime.h>

// Problem constants
#define N_BATCH 8
#define CI 8
#define CO 16
#define ODIM 66
#define OSP (66*66*66)        // 287496 per (n, co) slab
#define GROUPS 4

typedef _Float16 half8 __attribute__((ext_vector_type(8)));
typedef float f32x4 __attribute__((ext_vector_type(4)));

// MFMA conv tiling: block = (n, od-chunk of 6, 8 oh-rows). 8*66 = 528 positions
// = 33 tiles of 16 -> 3 waves x 11 tiles. K = 28 taps x 8 ci = 7 chunks of 32.
// Sliding window over od with a 3-plane LDS ring; lgkmcnt-only barriers.
//
// ROUND-7 LESSON (store-drain): with stage_issue at the TOP of step k (after
// epilogue(k-1)'s stores), the staging loads are the NEWEST vmem ops, so the
// compiler's wait before stage_write's cvts is vmcnt(0) -> drains 44 stores
// through HBM every k-step -> 1.3 TB/s stop-and-go (conv timed by traffic at
// 1/5 of achievable BW). Fix: issue loads at the END of step k (before the
// epilogue); then exactly 44 stores follow them and the wait can be
// vmcnt(44) -> stores never drain in-loop (T4). Counted vmcnt needs an EXACT
// store count, so stores are UNCONDITIONAL: the last oh-chunk overlaps
// (oh0=58) instead of predicating rows; overlap rows are recomputed
// bitwise-identically (benign same-value race) and excluded from stats by a
// VALU-only guard.
//
// REGISTER BUDGET (rounds 3-5): WRITE_SIZE responding to register edits proved
// scratch spill. Keep: launch_bounds(192,2) (cap 256), k-loop NOT unrolled,
// B-fragments re-read from LDS per chunk. xr (32) now lives across the
// epilogue; est. ~140 live <= 170 keeps 3 waves/SIMD (4 blocks/CU, LDS-bound).
#define OHT 8
#define NWAVES 3
#define TPW 11
#define NTHR 192
#define XIH 10                 // staged ih rows (8 + 2 halo)
#define XIW 68                 // staged iw (64 + 2+2 zero halo)
#define PLPOS (XIH*XIW)        // 680 positions per z-plane
#define PLPAIR (PLPOS/2)       // 340 float2 pair-positions
#define PLH (PLPOS*8)          // 5440 halfs per z-plane (10.88 KB)
#define RING 3                 // 3 active planes; new plane overwrites retiring one
#define LOD 6                  // od planes per block (11 chunks * 6 = 66)
#define NODC 11
#define WSZ (28*16*8)          // 3584 halfs, tap 27 = zero pad
#define XPLANE 262144          // 64*64*64 floats per (n,ci) plane

// lgkmcnt-only barrier: does NOT drain vmcnt (stores/loads keep flying).
#define LGKM_BARRIER() asm volatile("s_waitcnt lgkmcnt(0)\n\ts_barrier" ::: "memory")

// ws layout (floats): [0..31] sum, [32..63] sumsq
__global__ __launch_bounds__(64) void zero_stats(float* ws) {
    ws[threadIdx.x] = 0.0f;
}

// Issue the 16 (2 pair-pos x 8 ci) float2 global loads for one z-plane.
// Lanes consecutive -> pair-positions consecutive -> 8B/lane coalesced.
__device__ __forceinline__ void stage_issue(
    const float* __restrict__ x, size_t nbase, int id, int oh0, int tid,
    float2 xr[2][8], int sp[2], bool sok[2])
{
    #pragma unroll
    for (int it = 0; it < 2; ++it) {
        int p2  = tid + it * NTHR;            // < 384, valid if p2 < 340
        int row = p2 / 34;
        int u   = p2 - row * 34;
        int iw0 = 2 * u - 2;                  // even; pair (iw0, iw0+1)
        int ih  = oh0 - 2 + row;
        bool ok = (p2 < PLPAIR) & ((unsigned)id < 64u) &
                  ((unsigned)ih < 64u) & ((unsigned)iw0 < 63u);
        size_t base = nbase + (ok ? ((size_t)id * 4096 + (size_t)(ih * 64 + iw0)) : 0);
        #pragma unroll
        for (int ci = 0; ci < 8; ++ci)
            xr[it][ci] = *(const float2*)&x[base + (size_t)ci * XPLANE];  // clamped, safe, 8B-aligned
        sp[it] = p2; sok[it] = ok;
    }
}

// Convert + publish one staged plane into ring slot (2x contiguous b128 per
// pair, conflict-free). The cvts' implicit wait is vmcnt(44): exactly the 44
// unconditional epilogue stores issued after these loads may stay in flight.
__device__ __forceinline__ void stage_write(
    _Float16* XT, int slot, const float2 xr[2][8], const int sp[2], const bool sok[2])
{
    #pragma unroll
    for (int it = 0; it < 2; ++it) {
        if (sp[it] < PLPAIR) {
            half8 h0, h1;
            #pragma unroll
            for (int ci = 0; ci < 8; ++ci) {
                h0[ci] = sok[it] ? (_Float16)xr[it][ci].x : (_Float16)0.0f;
                h1[ci] = sok[it] ? (_Float16)xr[it][ci].y : (_Float16)0.0f;
            }
            _Float16* dst = &XT[slot * PLH + sp[it] * 16];
            *(half8*)dst = h0;
            *(half8*)(dst + 8) = h1;
        }
    }
}

__global__ __launch_bounds__(NTHR, 2) void conv_mfma(
    const float* __restrict__ x, const float* __restrict__ w,
    float* __restrict__ out, float* __restrict__ stats)
{
    __shared__ _Float16 XT[RING * PLH];   // 32,640 B ring of z-planes [slot][pos][ci]
    __shared__ _Float16 WT[WSZ];          // 7,168 B  [t][co][ci], tap 27 = zeros
    __shared__ float reds[2][NWAVES][GROUPS];

    const int tid = threadIdx.x;
    const int n   = blockIdx.z;
    const int od0 = blockIdx.y * LOD;
    const bool tail = (blockIdx.x == 8);
    const int oh0 = tail ? 58 : blockIdx.x * OHT;   // chunk 8 overlaps rows 58-63

    // Stage weights (fp16 round-trip per reference). Thread owns one (t,co).
    for (int i = tid; i < 28 * 16; i += NTHR) {
        int t = i >> 4, co = i & 15;
        half8 h;
        #pragma unroll
        for (int ci = 0; ci < 8; ++ci) {
            float v = (t < 27) ? w[(ci * 16 + co) * 27 + t] : 0.0f;
            h[ci] = (_Float16)v;
        }
        *(half8*)&WT[i * 8] = h;
    }

    const size_t nbase = (size_t)(n * CI) * XPLANE;

    // Prologue: planes j=0..2 (ids od0-2..od0) into ring slots 0..2.
    {
        float2 pxr[2][8]; int psp[2]; bool pok[2];
        #pragma unroll
        for (int j = 0; j < 3; ++j) {
            stage_issue(x, nbase, od0 - 2 + j, oh0, tid, pxr, psp, pok);
            stage_write(XT, j, pxr, psp, pok);
        }
    }

    float2 xr[2][8]; int sp[2]; bool sok[2]; // in-flight staging registers (T14)
    // Loads for step-0's stage_write target (plane id od0+1) go in flight now.
    stage_issue(x, nbase, od0 + 1, oh0, tid, xr, sp, sok);

    LGKM_BARRIER();   // WT + 3 planes visible (prologue cvts consumed their loads)

    const int lane = tid & 63;
    const int wv   = tid >> 6;
    const int q    = lane >> 4;     // tap-within-chunk (A/B k), row-block (D)
    const int col  = lane & 15;     // co (B/D), position m (A)

    // Per-chunk tap decomposition. t = c*4+q; t=27 clamps to 26 for addressing
    // (its WT row is zero so the A value is irrelevant).
    // TRANSPOSED-CONV FLIP: reference flips w before the correlation, so tap
    // (kd,kh,kw) in original w indexing reads input id = od - kd, ih = oh - kh,
    // iw = ow - kw. Hence plane j = k + (2 - kd)  (NOT k + kd — that bug cost
    // round 2), and sub[] is SUBTRACTED from the (+2,+2)-offset base.
    int sub[7], kdc[7];
    #pragma unroll
    for (int c = 0; c < 7; ++c) {
        int t = c * 4 + q;
        if (t > 26) t = 26;
        int kd = t / 9, r = t - kd * 9, kh = r / 3, kw = r - kh * 3;
        sub[c] = (kh * XIW + kw) * 8;   // within-plane tap offset (halfs), subtracted
        kdc[c] = 2 - kd;                // plane j = k + (2-kd) -> slot (km3+kdc) wrap 3
    }
    // B-fragment LDS base for this lane: WT[(t*16+col)*8], t = c*4+q.
    const int wtb = (q * 16 + col) * 8;   // + c*512 per chunk

    // Within-plane base address per tile: p = (wv*11+i)*16 + col in 8x66 grid.
    int basein[TPW];
    #pragma unroll
    for (int i = 0; i < TPW; ++i) {
        int p   = (wv * TPW + i) * 16 + col;
        int ohl = p / 66, ow = p - ohl * 66;
        basein[i] = ((ohl + 2) * XIW + (ow + 2)) * 8;
    }

    float s = 0.0f, ss = 0.0f;               // stats accumulated across all LOD ods
    const int co = col;
    float* slab = out + (size_t)(n * CO + co) * OSP + (size_t)od0 * 4356 + oh0 * 66;

    int km3 = 0;                             // k mod 3, maintained incrementally

    #pragma unroll 1
    for (int k = 0; k < LOD; ++k) {
        f32x4 acc[TPW];
        #pragma unroll
        for (int i = 0; i < TPW; ++i) acc[i] = (f32x4){0.f, 0.f, 0.f, 0.f};

        int aoffc[7];   // ring slot base + tap offset for this od
        #pragma unroll
        for (int c = 0; c < 7; ++c) {
            int slot = km3 + kdc[c];
            slot = (slot >= 3) ? slot - 3 : slot;
            aoffc[c] = slot * PLH - sub[c];
        }

        // 7 chunks x (1 bfrag ds_read + 11 a ds_read + 11 MFMA); c outer keeps
        // the 11 inner MFMAs independent. bfrag comes from LDS each chunk
        // (saves 28 live VGPRs; WT is read-only so barrier-safe).
        #pragma unroll
        for (int c = 0; c < 7; ++c) {
            half8 bf = *(const half8*)&WT[wtb + c * 512];
            #pragma unroll
            for (int i = 0; i < TPW; ++i) {
                half8 a = *(const half8*)&XT[basein[i] + aoffc[c]];
                acc[i] = __builtin_amdgcn_mfma_f32_16x16x32_f16(a, bf, acc[i], 0, 0, 0);
            }
        }

        if (k < LOD - 1) {
            LGKM_BARRIER();                   // barrier1: all waves done reading slot km3
            stage_write(XT, km3, xr, sp, sok); // waits vmcnt(44): loads done, stores fly
            LGKM_BARRIER();                   // barrier2: staged plane visible
            // Issue loads for the NEXT stage_write now, BEFORE this step's
            // epilogue stores, so next step's wait can be a counted vmcnt(44).
            if (k < LOD - 2)
                stage_issue(x, nbase, od0 + k + 2, oh0, tid, xr, sp, sok);
        }

        // Epilogue for od = od0+k: ReLU + 44 UNCONDITIONAL stores + stats.
        // Tail chunk (oh0=58) recomputes rows 58-63 identically to chunk 7
        // (benign same-value write race) and excludes them from stats.
        #pragma unroll
        for (int i = 0; i < TPW; ++i) {
            #pragma unroll
            for (int r = 0; r < 4; ++r) {
                int p   = (wv * TPW + i) * 16 + q * 4 + r;
                int ohl = p / 66, ow = p - ohl * 66;
                float v = fmaxf(acc[i][r], 0.0f);
                slab[ohl * 66 + ow] = v;
                if (!tail || ohl >= 6) {       // VALU-only guard, vmem count exact
                    s += v;
                    ss = fmaf(v, v, ss);
                }
            }
        }

        slab += 4356;
        km3 = (km3 == 2) ? 0 : km3 + 1;
    }

    // Reduce: xor16/32 merges lanes with same co; xor1/2 merges the 4 co of a group.
    s += __shfl_xor(s, 16, 64);  ss += __shfl_xor(ss, 16, 64);
    s += __shfl_xor(s, 32, 64);  ss += __shfl_xor(ss, 32, 64);
    s += __shfl_xor(s, 1, 64);   ss += __shfl_xor(ss, 1, 64);
    s += __shfl_xor(s, 2, 64);   ss += __shfl_xor(ss, 2, 64);
    if (lane < 16 && (lane & 3) == 0) {
        reds[0][wv][lane >> 2] = s;
        reds[1][wv][lane >> 2] = ss;
    }
    __syncthreads();
    if (tid < GROUPS) {
        float ts = 0.0f, tss = 0.0f;
        #pragma unroll
        for (int v = 0; v < NWAVES; ++v) { ts += reds[0][v][tid]; tss += reds[1][v][tid]; }
        atomicAdd(&stats[n * GROUPS + tid], ts);
        atomicAdd(&stats[32 + n * GROUPS + tid], tss);
    }
}

// In-place normalize: out = (y - mean) * rstd * gamma + beta.
// finalize folded in: each block derives mean/rstd from the raw sums (cheap).
#define NORM_ITER 8
#define NORM_NTHR 256
__global__ __launch_bounds__(NORM_NTHR) void norm_kernel(
    float* __restrict__ out, const float* __restrict__ ws,
    const float* __restrict__ gamma, const float* __restrict__ beta)
{
    const int slab = blockIdx.y;           // n*16 + co
    const int n  = slab >> 4;
    const int co = slab & 15;
    const int gi = n * GROUPS + (co >> 2);
    const float cnt  = 4.0f * (float)OSP;
    const float mean = ws[gi] / cnt;
    const float var  = ws[32 + gi] / cnt - mean * mean;
    const float rstd = rsqrtf(var + 1e-5f);
    const float scale = rstd * gamma[co];
    const float shift = beta[co] - mean * scale;

    float4* p = (float4*)(out + (size_t)slab * OSP);
    const int base = blockIdx.x * (NORM_NTHR * NORM_ITER) + threadIdx.x;
    #pragma unroll
    for (int it = 0; it < NORM_ITER; ++it) {
        const int idx = base + it * NORM_NTHR;
        if (idx < OSP / 4) {
            float4 v = p[idx];
            v.x = fmaf(v.x, scale, shift);
            v.y = fmaf(v.y, scale, shift);
            v.z = fmaf(v.z, scale, shift);
            v.w = fmaf(v.w, scale, shift);
            p[idx] = v;
        }
    }
}

extern "C" void kernel_launch(void* const* d_in, const int* in_sizes, int n_in,
                              void* d_out, int out_size, void* d_ws, size_t ws_size,
                              hipStream_t stream) {
    const float* x     = (const float*)d_in[0];
    const float* w     = (const float*)d_in[1];
    const float* gamma = (const float*)d_in[2];
    const float* beta  = (const float*)d_in[3];
    float* out = (float*)d_out;
    float* ws  = (float*)d_ws;

    zero_stats<<<1, 64, 0, stream>>>(ws);

    dim3 grid1((ODIM + OHT - 1) / OHT, NODC, N_BATCH);     // (9, 11, 8) = 792 blocks
    conv_mfma<<<grid1, NTHR, 0, stream>>>(x, w, out, ws);

    const int f4_per_slab = OSP / 4;                       // 71874
    dim3 grid2((f4_per_slab + NORM_NTHR * NORM_ITER - 1) / (NORM_NTHR * NORM_ITER),
               N_BATCH * CO);                              // (36, 128)
    norm_kernel<<<grid2, NORM_NTHR, 0, stream>>>(out, ws, gamma, beta);
}